// Round 4
// baseline (261.601 us; speedup 1.0000x reference)
//
#include <hip/hip_runtime.h>
#include <cstdint>
#include <cstddef>

using f32x4 = __attribute__((ext_vector_type(4))) float;

#define TDIM 2048
#define HDIM 2048
#define IDIM 1408
#define NEXP 8
#define NKB1 16   // H/128
#define NNB1 11   // I/128
#define NKB2 11   // I/128
#define MAXM 4096 // T*TOPK
#define LDA 144   // padded LDS row stride (128 data + 16 pad)

__device__ __forceinline__ f32x4 mfma_fp8(long a, long b, f32x4 c) {
  return __builtin_amdgcn_mfma_f32_16x16x32_fp8_fp8(a, b, c, 0, 0, 0);
}

// single f32 -> fp8 e4m3fn byte (RNE, pre-clamped like reference's clip).
__device__ __forceinline__ uint32_t f8_1(float q) {
  q = fminf(fmaxf(q, -448.f), 448.f);
  return (uint32_t)__builtin_amdgcn_cvt_pk_fp8_f32(q, q, 0, false) & 0xffu;
}

__device__ __forceinline__ float bf16_to_f32(uint32_t bits16) {
  union { uint32_t u; float f; } c;
  c.u = bits16 << 16;
  return c.f;
}

// ============ kernel -1: sniff weight storage dtype ============
// e4m3-exact values stored as f32-LE have low uint16 == 0 always.
// bf16 storage: even-indexed uint16s are bf16 of random weights -> not all zero.
__global__ void sniff_kernel(const uint16_t* __restrict__ a,
                             const uint16_t* __restrict__ b,
                             int* __restrict__ modes) {
  if (threadIdx.x == 0 && blockIdx.x == 0) {
    unsigned acc = 0;
    for (int i = 0; i < 128; ++i) acc |= a[2 * i];
    modes[0] = (acc == 0) ? 1 : 0;   // 1 = f32 storage, 0 = bf16 storage
    acc = 0;
    for (int i = 0; i < 128; ++i) acc |= b[2 * i];
    modes[1] = (acc == 0) ? 1 : 0;
  }
}

// ============ kernel 0: repack weight values -> fp8 bytes (dual dtype) ============
__global__ void repack_kernel(const void* __restrict__ in, uint8_t* __restrict__ out,
                              int n8, const int* __restrict__ modes, int midx) {
  const int i = blockIdx.x * 256 + threadIdx.x;
  if (i >= n8) return;
  const int m = modes[midx];
  float f[8];
  if (m == 1) {            // f32 storage
    const float4* p = (const float4*)in;
    float4 a = p[2 * i], b = p[2 * i + 1];
    f[0] = a.x; f[1] = a.y; f[2] = a.z; f[3] = a.w;
    f[4] = b.x; f[5] = b.y; f[6] = b.z; f[7] = b.w;
  } else {                 // bf16 storage
    uint4 v = ((const uint4*)in)[i];
#pragma unroll
    for (int j = 0; j < 4; ++j) {
      uint32_t w = (&v.x)[j];
      f[2 * j]     = bf16_to_f32(w & 0xffffu);
      f[2 * j + 1] = bf16_to_f32(w >> 16);
    }
  }
  uint32_t lo = 0, hi = 0;
#pragma unroll
  for (int j = 0; j < 8; ++j) {
    uint32_t b8 = f8_1(f[j]);
    if (j < 4) lo |= b8 << (8 * j);
    else       hi |= b8 << (8 * (j - 4));
  }
  ((uint2*)out)[i] = make_uint2(lo, hi);
}

// ============ kernel 1: per-(row,128-block) quantize of hidden_states ============
__global__ void quantx_kernel(const float* __restrict__ x,
                              uint8_t* __restrict__ xq, float* __restrict__ xs) {
  const int gid = blockIdx.x * 4 + (threadIdx.x >> 6);
  const int lane = threadIdx.x & 63;
  const int r = gid >> 4, kb = gid & 15;
  const float2 v = *(const float2*)(x + (size_t)r * HDIM + kb * 128 + lane * 2);
  float a = fmaxf(fabsf(v.x), fabsf(v.y));
#pragma unroll
  for (int d = 1; d < 64; d <<= 1) a = fmaxf(a, __shfl_xor(a, d));
  const float s = fmaxf(a, 1e-12f) / 448.f;
  const uint32_t b0 = f8_1(v.x / s);
  const uint32_t b1 = f8_1(v.y / s);
  *(uint16_t*)(xq + (size_t)r * HDIM + kb * 128 + lane * 2) = (uint16_t)(b0 | (b1 << 8));
  if (lane == 0) xs[r * 16 + kb] = s;
}

// ============ kernel 2: routing -> per-expert slot lists (slot = t*2+k) ============
__global__ void route_kernel(const void* __restrict__ idxraw,
                             int* __restrict__ list, int* __restrict__ cnt) {
  const long long* p = (const long long*)idxraw;
  unsigned hi = 0;
#pragma unroll
  for (int j = 0; j < 16; ++j) hi |= (unsigned)((unsigned long long)p[j] >> 32);
  const int i = blockIdx.x * 256 + threadIdx.x;
  int e;
  if (hi == 0) {
    e = (int)p[i];                       // int64 storage
  } else {
    long long v = p[i >> 1];             // int32 storage: two slots per qword
    e = (int)((i & 1) ? (v >> 32) : (v & 0xffffffffLL));
  }
  e &= 7;
  const int pos = atomicAdd(&cnt[e], 1);
  list[e * MAXM + pos] = i;
}

// ============ kernel 3: gate_up GEMM (fp8 MFMA, block scales) + silu*up + h-quant ============
__global__ __launch_bounds__(512) void gemm1_kernel(
    const uint8_t* __restrict__ xq, const float* __restrict__ xs,
    const uint8_t* __restrict__ w, const float* __restrict__ wscl,
    const int* __restrict__ list, const int* __restrict__ cnt,
    uint8_t* __restrict__ hq, float* __restrict__ hs) {
  const int e = blockIdx.z, mt = blockIdx.y, nb = blockIdx.x;
  const int M = cnt[e];
  if (mt * 128 >= M) return;
  __shared__ __align__(16) uint8_t As[128 * LDA];
  __shared__ __align__(16) uint8_t Bg[128 * LDA];
  __shared__ __align__(16) uint8_t Bu[128 * LDA];
  __shared__ int slots[128];
  __shared__ __align__(16) float sxs[128];
  __shared__ __align__(16) float amx[512];
  const int tid = threadIdx.x, lane = tid & 63, wid = tid >> 6;
  const int wr = wid >> 2, wc = wid & 3;
  if (tid < 128) {
    int m = mt * 128 + tid;
    slots[tid] = list[e * MAXM + (m < M ? m : 0)];
  }
  __syncthreads();
  const int srow = tid >> 3;
  const int cj = (tid & 7) << 4;   // linear 16B chunk, no swizzle
  const long tokA0 = slots[srow] >> 1;
  const long tokA1 = slots[srow + 64] >> 1;
  const int my_tok = (tid < 128) ? (slots[tid] >> 1) : 0;
  const uint8_t* pA0 = xq + tokA0 * HDIM + cj;
  const uint8_t* pA1 = xq + tokA1 * HDIM + cj;
  const size_t wb = (size_t)e * (2 * IDIM) * HDIM;
  const uint8_t* pG0 = w + wb + (size_t)(nb * 128 + srow) * HDIM + cj;
  const uint8_t* pU0 = w + wb + (size_t)(IDIM + nb * 128 + srow) * HDIM + cj;
  const float* wsg = wscl + (size_t)e * 352 + nb * 16;   // (E,22,16): gate block nb
  const float* wsu = wsg + 176;                          // up block 11+nb
  const float* pSX = xs + (size_t)my_tok * 16;
  f32x4 accg[4][2] = {};
  f32x4 accu[4][2] = {};
  const int kbyte = (lane >> 4) << 3;
  f32x4 ra0, ra1, rg0, rg1, ru0, ru1;
  float rs;
  ra0 = *(const f32x4*)(pA0);
  ra1 = *(const f32x4*)(pA1);
  rg0 = *(const f32x4*)(pG0);
  rg1 = *(const f32x4*)(pG0 + 64 * HDIM);
  ru0 = *(const f32x4*)(pU0);
  ru1 = *(const f32x4*)(pU0 + 64 * HDIM);
  rs = (tid < 128) ? pSX[0] : 0.f;
  for (int kb = 0; kb < NKB1; ++kb) {
    __syncthreads();
    *(f32x4*)(As + srow * LDA + cj) = ra0;
    *(f32x4*)(As + (srow + 64) * LDA + cj) = ra1;
    *(f32x4*)(Bg + srow * LDA + cj) = rg0;
    *(f32x4*)(Bg + (srow + 64) * LDA + cj) = rg1;
    *(f32x4*)(Bu + srow * LDA + cj) = ru0;
    *(f32x4*)(Bu + (srow + 64) * LDA + cj) = ru1;
    if (tid < 128) sxs[tid] = rs;
    __syncthreads();
    if (kb + 1 < NKB1) {
      const int ko = (kb + 1) << 7;
      ra0 = *(const f32x4*)(pA0 + ko);
      ra1 = *(const f32x4*)(pA1 + ko);
      rg0 = *(const f32x4*)(pG0 + ko);
      rg1 = *(const f32x4*)(pG0 + 64 * HDIM + ko);
      ru0 = *(const f32x4*)(pU0 + ko);
      ru1 = *(const f32x4*)(pU0 + 64 * HDIM + ko);
      rs = (tid < 128) ? pSX[kb + 1] : 0.f;
    }
    const float swg = wsg[kb];
    const float swu = wsu[kb];
    long af[4][4], bgf[2][4], buf_[2][4];
#pragma unroll
    for (int mi = 0; mi < 4; ++mi) {
      const int r = wr * 64 + mi * 16 + (lane & 15);
      const uint8_t* bp = As + r * LDA;
#pragma unroll
      for (int kc = 0; kc < 4; ++kc)
        af[mi][kc] = *(const long*)(bp + (kc << 5) + kbyte);
    }
#pragma unroll
    for (int ni = 0; ni < 2; ++ni) {
      const int r = wc * 32 + ni * 16 + (lane & 15);
      const uint8_t* bpg = Bg + r * LDA;
      const uint8_t* bpu = Bu + r * LDA;
#pragma unroll
      for (int kc = 0; kc < 4; ++kc) {
        bgf[ni][kc] = *(const long*)(bpg + (kc << 5) + kbyte);
        buf_[ni][kc] = *(const long*)(bpu + (kc << 5) + kbyte);
      }
    }
    f32x4 sx[4];
#pragma unroll
    for (int mi = 0; mi < 4; ++mi)
      sx[mi] = *(const f32x4*)(sxs + wr * 64 + mi * 16 + ((lane >> 4) << 2));
#pragma unroll
    for (int mi = 0; mi < 4; ++mi)
#pragma unroll
      for (int ni = 0; ni < 2; ++ni) {
        f32x4 pg = {0.f, 0.f, 0.f, 0.f};
        f32x4 pu = {0.f, 0.f, 0.f, 0.f};
#pragma unroll
        for (int kc = 0; kc < 4; ++kc) {
          pg = mfma_fp8(af[mi][kc], bgf[ni][kc], pg);
          pu = mfma_fp8(af[mi][kc], buf_[ni][kc], pu);
        }
#pragma unroll
        for (int j = 0; j < 4; ++j) {
          accg[mi][ni][j] += pg[j] * (sx[mi][j] * swg);
          accu[mi][ni][j] += pu[j] * (sx[mi][j] * swu);
        }
      }
  }
  f32x4 hv[4][2];
  f32x4 rmax[4];
#pragma unroll
  for (int mi = 0; mi < 4; ++mi) {
#pragma unroll
    for (int ni = 0; ni < 2; ++ni)
#pragma unroll
      for (int j = 0; j < 4; ++j) {
        float g = accg[mi][ni][j];
        float u = accu[mi][ni][j];
        float h = (g / (1.f + expf(-g))) * u;
        hv[mi][ni][j] = h;
        float ah = fabsf(h);
        rmax[mi][j] = (ni == 0) ? ah : fmaxf(rmax[mi][j], ah);
      }
#pragma unroll
    for (int d = 1; d < 16; d <<= 1)
#pragma unroll
      for (int j = 0; j < 4; ++j)
        rmax[mi][j] = fmaxf(rmax[mi][j], __shfl_xor(rmax[mi][j], d));
  }
  __syncthreads();
  if ((lane & 15) == 0) {
#pragma unroll
    for (int mi = 0; mi < 4; ++mi)
#pragma unroll
      for (int j = 0; j < 4; ++j) {
        int row = wr * 64 + mi * 16 + ((lane >> 4) << 2) + j;
        amx[row * 4 + wc] = rmax[mi][j];
      }
  }
  __syncthreads();
  const int Mrem = M - mt * 128;
#pragma unroll
  for (int mi = 0; mi < 4; ++mi)
#pragma unroll
    for (int j = 0; j < 4; ++j) {
      const int row = wr * 64 + mi * 16 + ((lane >> 4) << 2) + j;
      f32x4 a4 = *(const f32x4*)(amx + row * 4);
      float am = fmaxf(fmaxf(a4[0], a4[1]), fmaxf(a4[2], a4[3]));
      float s = fmaxf(am, 1e-12f) / 448.f;
      if (row < Mrem) {
        const int slot = slots[row];
        uint8_t* hp = hq + (size_t)slot * IDIM + nb * 128 + wc * 32 + (lane & 15);
        hp[0]  = (uint8_t)f8_1(hv[mi][0][j] / s);
        hp[16] = (uint8_t)f8_1(hv[mi][1][j] / s);
        if (wc == 0 && (lane & 15) == 0) hs[slot * 11 + nb] = s;
      }
    }
}

// ============ kernel 4: down GEMM (fp8 MFMA, block scales) + rw-weighted scatter-add ============
__global__ __launch_bounds__(512) void gemm2_kernel(
    const uint8_t* __restrict__ hq, const float* __restrict__ hs,
    const uint8_t* __restrict__ w, const float* __restrict__ wscl,
    const int* __restrict__ list, const int* __restrict__ cnt,
    const float* __restrict__ tkw, float* __restrict__ out) {
  const int e = blockIdx.z, mt = blockIdx.y, nt = blockIdx.x;
  const int M = cnt[e];
  if (mt * 128 >= M) return;
  __shared__ __align__(16) uint8_t As[128 * LDA];
  __shared__ __align__(16) uint8_t Bs[256 * LDA];
  __shared__ int slots[128];
  __shared__ float rwl[128];
  __shared__ __align__(16) float sxs[128];
  const int tid = threadIdx.x, lane = tid & 63, wid = tid >> 6;
  const int wr = wid >> 2, wc = wid & 3;
  if (tid < 128) {
    int m = mt * 128 + tid;
    int slot = list[e * MAXM + (m < M ? m : 0)];
    slots[tid] = slot;
    rwl[tid] = (m < M) ? tkw[slot] : 0.f;
  }
  __syncthreads();
  const int srow = tid >> 3;
  const int cj = (tid & 7) << 4;
  const long slotA0 = slots[srow];
  const long slotA1 = slots[srow + 64];
  const int my_slot = (tid < 128) ? slots[tid] : 0;
  const uint8_t* pA0 = hq + slotA0 * IDIM + cj;
  const uint8_t* pA1 = hq + slotA1 * IDIM + cj;
  const uint8_t* pB = w + (size_t)e * HDIM * IDIM + (size_t)(nt * 256 + srow) * IDIM + cj;
  const float* wsd = wscl + (size_t)e * 176 + (nt * 2 + (wc >> 1)) * 11;  // (E,16,11)
  const float* pSX = hs + (size_t)my_slot * 11;
  f32x4 acc[4][4] = {};
  const int kbyte = (lane >> 4) << 3;
  f32x4 ra0, ra1, rb0, rb1, rb2, rb3;
  float rs;
  ra0 = *(const f32x4*)(pA0);
  ra1 = *(const f32x4*)(pA1);
  rb0 = *(const f32x4*)(pB);
  rb1 = *(const f32x4*)(pB + (size_t)64 * IDIM);
  rb2 = *(const f32x4*)(pB + (size_t)128 * IDIM);
  rb3 = *(const f32x4*)(pB + (size_t)192 * IDIM);
  rs = (tid < 128) ? pSX[0] : 0.f;
  for (int kb = 0; kb < NKB2; ++kb) {
    __syncthreads();
    *(f32x4*)(As + srow * LDA + cj) = ra0;
    *(f32x4*)(As + (srow + 64) * LDA + cj) = ra1;
    *(f32x4*)(Bs + srow * LDA + cj) = rb0;
    *(f32x4*)(Bs + (srow + 64) * LDA + cj) = rb1;
    *(f32x4*)(Bs + (srow + 128) * LDA + cj) = rb2;
    *(f32x4*)(Bs + (srow + 192) * LDA + cj) = rb3;
    if (tid < 128) sxs[tid] = rs;
    __syncthreads();
    if (kb + 1 < NKB2) {
      const int ko = (kb + 1) << 7;
      ra0 = *(const f32x4*)(pA0 + ko);
      ra1 = *(const f32x4*)(pA1 + ko);
      rb0 = *(const f32x4*)(pB + ko);
      rb1 = *(const f32x4*)(pB + (size_t)64 * IDIM + ko);
      rb2 = *(const f32x4*)(pB + (size_t)128 * IDIM + ko);
      rb3 = *(const f32x4*)(pB + (size_t)192 * IDIM + ko);
      rs = (tid < 128) ? pSX[kb + 1] : 0.f;
    }
    const float swd = wsd[kb];
    long af[4][4], bf[4][4];
#pragma unroll
    for (int mi = 0; mi < 4; ++mi) {
      const int r = wr * 64 + mi * 16 + (lane & 15);
      const uint8_t* bp = As + r * LDA;
#pragma unroll
      for (int kc = 0; kc < 4; ++kc)
        af[mi][kc] = *(const long*)(bp + (kc << 5) + kbyte);
    }
#pragma unroll
    for (int ni = 0; ni < 4; ++ni) {
      const int r = wc * 64 + ni * 16 + (lane & 15);
      const uint8_t* bp = Bs + r * LDA;
#pragma unroll
      for (int kc = 0; kc < 4; ++kc)
        bf[ni][kc] = *(const long*)(bp + (kc << 5) + kbyte);
    }
    f32x4 sx[4];
#pragma unroll
    for (int mi = 0; mi < 4; ++mi)
      sx[mi] = *(const f32x4*)(sxs + wr * 64 + mi * 16 + ((lane >> 4) << 2));
#pragma unroll
    for (int mi = 0; mi < 4; ++mi)
#pragma unroll
      for (int ni = 0; ni < 4; ++ni) {
        f32x4 p = {0.f, 0.f, 0.f, 0.f};
#pragma unroll
        for (int kc = 0; kc < 4; ++kc) p = mfma_fp8(af[mi][kc], bf[ni][kc], p);
#pragma unroll
        for (int j = 0; j < 4; ++j) acc[mi][ni][j] += p[j] * (sx[mi][j] * swd);
      }
  }
  const int Mrem = M - mt * 128;
#pragma unroll
  for (int mi = 0; mi < 4; ++mi)
#pragma unroll
    for (int j = 0; j < 4; ++j) {
      const int row = wr * 64 + mi * 16 + ((lane >> 4) << 2) + j;
      if (row < Mrem) {
        const int slot = slots[row];
        const float rw = rwl[row];
        float* op = out + (size_t)(slot >> 1) * HDIM + nt * 256 + wc * 64 + (lane & 15);
#pragma unroll
        for (int ni = 0; ni < 4; ++ni) atomicAdd(op + ni * 16, rw * acc[mi][ni][j]);
      }
    }
}

extern "C" void kernel_launch(void* const* d_in, const int* in_sizes, int n_in,
                              void* d_out, int out_size, void* d_ws, size_t ws_size,
                              hipStream_t stream) {
  const float* hidden = (const float*)d_in[0];
  const void* topk_idx = d_in[1];
  const float* topk_w = (const float*)d_in[2];
  const void* gup_raw = d_in[3];   // fp8 values held as f32 or bf16 (sniffed)
  const float* gup_s = (const float*)d_in[4];
  const void* dwn_raw = d_in[5];
  const float* dwn_s = (const float*)d_in[6];
  float* out = (float*)d_out;
  uint8_t* ws = (uint8_t*)d_ws;
  // workspace layout (~79.6 MB)
  uint8_t* xq = ws;                           //  4,194,304
  float* xs = (float*)(ws + 4194304);         //    131,072
  uint8_t* hq = ws + 4325376;                 //  5,767,168
  float* hs = (float*)(ws + 10092544);        //    180,224
  int* list = (int*)(ws + 10272768);          //    131,072
  int* cnt = (int*)(ws + 10403840);           //         64
  int* modes = (int*)(ws + 10403904);         //         64
  uint8_t* gq = ws + 10403968;                // 46,137,344 (gate_up fp8)
  uint8_t* dq = ws + 56541312;                // 23,068,672 (down fp8)
  (void)in_sizes; (void)n_in; (void)ws_size;

  hipMemsetAsync(cnt, 0, 32, stream);
  hipMemsetAsync(out, 0, (size_t)out_size * sizeof(float), stream);
  sniff_kernel<<<1, 64, 0, stream>>>((const uint16_t*)gup_raw, (const uint16_t*)dwn_raw, modes);
  repack_kernel<<<(5767168 + 255) / 256, 256, 0, stream>>>(gup_raw, gq, 5767168, modes, 0);
  repack_kernel<<<(2883584 + 255) / 256, 256, 0, stream>>>(dwn_raw, dq, 2883584, modes, 1);
  quantx_kernel<<<8192, 256, 0, stream>>>(hidden, xq, xs);
  route_kernel<<<16, 256, 0, stream>>>(topk_idx, list, cnt);
  gemm1_kernel<<<dim3(NNB1, MAXM / 128, NEXP), 512, 0, stream>>>(xq, xs, gq, gup_s, list, cnt, hq, hs);
  gemm2_kernel<<<dim3(HDIM / 256, MAXM / 128, NEXP), 512, 0, stream>>>(hq, hs, dq, dwn_s, list, cnt, topk_w, out);
}

// Round 5
// 260.289 us; speedup vs baseline: 1.0050x; 1.0050x over previous
//
#include <hip/hip_runtime.h>
#include <cstdint>
#include <cstddef>

using f32x4 = __attribute__((ext_vector_type(4))) float;

#define TDIM 2048
#define HDIM 2048
#define IDIM 1408
#define NEXP 8
#define NKB1 16   // H/128
#define NNB1 11   // I/128
#define NKB2 11   // I/128
#define MAXM 4096 // T*TOPK
#define LDA 144   // padded LDS row stride (128 data + 16 pad)

__device__ __forceinline__ f32x4 mfma_fp8(long a, long b, f32x4 c) {
  return __builtin_amdgcn_mfma_f32_16x16x32_fp8_fp8(a, b, c, 0, 0, 0);
}

// single f32 -> fp8 e4m3fn byte (RNE, pre-clamped like reference's clip).
__device__ __forceinline__ uint32_t f8_1(float q) {
  q = fminf(fmaxf(q, -448.f), 448.f);
  return (uint32_t)__builtin_amdgcn_cvt_pk_fp8_f32(q, q, 0, false) & 0xffu;
}

__device__ __forceinline__ float bf16_to_f32(uint32_t bits16) {
  union { uint32_t u; float f; } c;
  c.u = bits16 << 16;
  return c.f;
}

// ============ kernel Z: zero output + cnt (replaces slow rocclr fills) ============
// 4096 blocks x 256 thr x float4 == 4,194,304 floats exactly.
__global__ void zero_kernel(float* __restrict__ out, int* __restrict__ cnt) {
  const int i = blockIdx.x * 256 + threadIdx.x;
  ((f32x4*)out)[i] = f32x4{0.f, 0.f, 0.f, 0.f};
  if (blockIdx.x == 0 && threadIdx.x < 8) cnt[threadIdx.x] = 0;
}

// ============ kernel -1: sniff weight storage dtype ============
// e4m3-exact values stored as f32-LE have low uint16 == 0 always.
__global__ void sniff_kernel(const uint16_t* __restrict__ a,
                             const uint16_t* __restrict__ b,
                             int* __restrict__ modes) {
  if (threadIdx.x == 0 && blockIdx.x == 0) {
    unsigned acc = 0;
    for (int i = 0; i < 128; ++i) acc |= a[2 * i];
    modes[0] = (acc == 0) ? 1 : 0;   // 1 = f32 storage, 0 = bf16 storage
    acc = 0;
    for (int i = 0; i < 128; ++i) acc |= b[2 * i];
    modes[1] = (acc == 0) ? 1 : 0;
  }
}

// ============ kernel 0: repack weight values -> fp8 bytes (dual dtype) ============
__global__ void repack_kernel(const void* __restrict__ in, uint8_t* __restrict__ out,
                              int n8, const int* __restrict__ modes, int midx) {
  const int i = blockIdx.x * 256 + threadIdx.x;
  if (i >= n8) return;
  const int m = modes[midx];
  float f[8];
  if (m == 1) {            // f32 storage
    const float4* p = (const float4*)in;
    float4 a = p[2 * i], b = p[2 * i + 1];
    f[0] = a.x; f[1] = a.y; f[2] = a.z; f[3] = a.w;
    f[4] = b.x; f[5] = b.y; f[6] = b.z; f[7] = b.w;
  } else {                 // bf16 storage
    uint4 v = ((const uint4*)in)[i];
#pragma unroll
    for (int j = 0; j < 4; ++j) {
      uint32_t w = (&v.x)[j];
      f[2 * j]     = bf16_to_f32(w & 0xffffu);
      f[2 * j + 1] = bf16_to_f32(w >> 16);
    }
  }
  uint32_t lo = 0, hi = 0;
#pragma unroll
  for (int j = 0; j < 8; ++j) {
    uint32_t b8 = f8_1(f[j]);
    if (j < 4) lo |= b8 << (8 * j);
    else       hi |= b8 << (8 * (j - 4));
  }
  ((uint2*)out)[i] = make_uint2(lo, hi);
}

// ============ kernel 1: per-(row,128-block) quantize of hidden_states ============
__global__ void quantx_kernel(const float* __restrict__ x,
                              uint8_t* __restrict__ xq, float* __restrict__ xs) {
  const int gid = blockIdx.x * 4 + (threadIdx.x >> 6);
  const int lane = threadIdx.x & 63;
  const int r = gid >> 4, kb = gid & 15;
  const float2 v = *(const float2*)(x + (size_t)r * HDIM + kb * 128 + lane * 2);
  float a = fmaxf(fabsf(v.x), fabsf(v.y));
#pragma unroll
  for (int d = 1; d < 64; d <<= 1) a = fmaxf(a, __shfl_xor(a, d));
  const float s = fmaxf(a, 1e-12f) / 448.f;
  const uint32_t b0 = f8_1(v.x / s);
  const uint32_t b1 = f8_1(v.y / s);
  *(uint16_t*)(xq + (size_t)r * HDIM + kb * 128 + lane * 2) = (uint16_t)(b0 | (b1 << 8));
  if (lane == 0) xs[r * 16 + kb] = s;
}

// ============ kernel 2: routing -> per-expert slot lists (slot = t*2+k) ============
__global__ void route_kernel(const void* __restrict__ idxraw,
                             int* __restrict__ list, int* __restrict__ cnt) {
  const long long* p = (const long long*)idxraw;
  unsigned hi = 0;
#pragma unroll
  for (int j = 0; j < 16; ++j) hi |= (unsigned)((unsigned long long)p[j] >> 32);
  const int i = blockIdx.x * 256 + threadIdx.x;
  int e;
  if (hi == 0) {
    e = (int)p[i];                       // int64 storage
  } else {
    long long v = p[i >> 1];             // int32 storage: two slots per qword
    e = (int)((i & 1) ? (v >> 32) : (v & 0xffffffffLL));
  }
  e &= 7;
  const int pos = atomicAdd(&cnt[e], 1);
  list[e * MAXM + pos] = i;
}

// ============ kernel 3: gate_up GEMM (fp8 MFMA, block scales) + silu*up + h-quant ============
__global__ __launch_bounds__(512) void gemm1_kernel(
    const uint8_t* __restrict__ xq, const float* __restrict__ xs,
    const uint8_t* __restrict__ w, const float* __restrict__ wscl,
    const int* __restrict__ list, const int* __restrict__ cnt,
    uint8_t* __restrict__ hq, float* __restrict__ hs) {
  const int e = blockIdx.z, mt = blockIdx.y, nb = blockIdx.x;
  const int M = cnt[e];
  if (mt * 128 >= M) return;
  __shared__ __align__(16) uint8_t As[128 * LDA];
  __shared__ __align__(16) uint8_t Bg[128 * LDA];
  __shared__ __align__(16) uint8_t Bu[128 * LDA];
  __shared__ int slots[128];
  __shared__ __align__(16) float sxs[128];
  __shared__ __align__(16) float amx[512];
  const int tid = threadIdx.x, lane = tid & 63, wid = tid >> 6;
  const int wr = wid >> 2, wc = wid & 3;
  if (tid < 128) {
    int m = mt * 128 + tid;
    slots[tid] = list[e * MAXM + (m < M ? m : 0)];
  }
  __syncthreads();
  const int srow = tid >> 3;
  const int cj = (tid & 7) << 4;   // linear 16B chunk, no swizzle
  const long tokA0 = slots[srow] >> 1;
  const long tokA1 = slots[srow + 64] >> 1;
  const int my_tok = (tid < 128) ? (slots[tid] >> 1) : 0;
  const uint8_t* pA0 = xq + tokA0 * HDIM + cj;
  const uint8_t* pA1 = xq + tokA1 * HDIM + cj;
  const size_t wb = (size_t)e * (2 * IDIM) * HDIM;
  const uint8_t* pG0 = w + wb + (size_t)(nb * 128 + srow) * HDIM + cj;
  const uint8_t* pU0 = w + wb + (size_t)(IDIM + nb * 128 + srow) * HDIM + cj;
  const float* wsg = wscl + (size_t)e * 352 + nb * 16;   // (E,22,16): gate block nb
  const float* wsu = wsg + 176;                          // up block 11+nb
  const float* pSX = xs + (size_t)my_tok * 16;
  f32x4 accg[4][2] = {};
  f32x4 accu[4][2] = {};
  const int kbyte = (lane >> 4) << 3;
  f32x4 ra0, ra1, rg0, rg1, ru0, ru1;
  float rs;
  ra0 = *(const f32x4*)(pA0);
  ra1 = *(const f32x4*)(pA1);
  rg0 = *(const f32x4*)(pG0);
  rg1 = *(const f32x4*)(pG0 + 64 * HDIM);
  ru0 = *(const f32x4*)(pU0);
  ru1 = *(const f32x4*)(pU0 + 64 * HDIM);
  rs = (tid < 128) ? pSX[0] : 0.f;
  for (int kb = 0; kb < NKB1; ++kb) {
    __syncthreads();
    *(f32x4*)(As + srow * LDA + cj) = ra0;
    *(f32x4*)(As + (srow + 64) * LDA + cj) = ra1;
    *(f32x4*)(Bg + srow * LDA + cj) = rg0;
    *(f32x4*)(Bg + (srow + 64) * LDA + cj) = rg1;
    *(f32x4*)(Bu + srow * LDA + cj) = ru0;
    *(f32x4*)(Bu + (srow + 64) * LDA + cj) = ru1;
    if (tid < 128) sxs[tid] = rs;
    __syncthreads();
    if (kb + 1 < NKB1) {
      const int ko = (kb + 1) << 7;
      ra0 = *(const f32x4*)(pA0 + ko);
      ra1 = *(const f32x4*)(pA1 + ko);
      rg0 = *(const f32x4*)(pG0 + ko);
      rg1 = *(const f32x4*)(pG0 + 64 * HDIM + ko);
      ru0 = *(const f32x4*)(pU0 + ko);
      ru1 = *(const f32x4*)(pU0 + 64 * HDIM + ko);
      rs = (tid < 128) ? pSX[kb + 1] : 0.f;
    }
    const float swg = wsg[kb];
    const float swu = wsu[kb];
    long af[4][4], bgf[2][4], buf_[2][4];
#pragma unroll
    for (int mi = 0; mi < 4; ++mi) {
      const int r = wr * 64 + mi * 16 + (lane & 15);
      const uint8_t* bp = As + r * LDA;
#pragma unroll
      for (int kc = 0; kc < 4; ++kc)
        af[mi][kc] = *(const long*)(bp + (kc << 5) + kbyte);
    }
#pragma unroll
    for (int ni = 0; ni < 2; ++ni) {
      const int r = wc * 32 + ni * 16 + (lane & 15);
      const uint8_t* bpg = Bg + r * LDA;
      const uint8_t* bpu = Bu + r * LDA;
#pragma unroll
      for (int kc = 0; kc < 4; ++kc) {
        bgf[ni][kc] = *(const long*)(bpg + (kc << 5) + kbyte);
        buf_[ni][kc] = *(const long*)(bpu + (kc << 5) + kbyte);
      }
    }
    f32x4 sx[4];
#pragma unroll
    for (int mi = 0; mi < 4; ++mi)
      sx[mi] = *(const f32x4*)(sxs + wr * 64 + mi * 16 + ((lane >> 4) << 2));
#pragma unroll
    for (int mi = 0; mi < 4; ++mi)
#pragma unroll
      for (int ni = 0; ni < 2; ++ni) {
        f32x4 pg = {0.f, 0.f, 0.f, 0.f};
        f32x4 pu = {0.f, 0.f, 0.f, 0.f};
#pragma unroll
        for (int kc = 0; kc < 4; ++kc) {
          pg = mfma_fp8(af[mi][kc], bgf[ni][kc], pg);
          pu = mfma_fp8(af[mi][kc], buf_[ni][kc], pu);
        }
#pragma unroll
        for (int j = 0; j < 4; ++j) {
          accg[mi][ni][j] += pg[j] * (sx[mi][j] * swg);
          accu[mi][ni][j] += pu[j] * (sx[mi][j] * swu);
        }
      }
  }
  f32x4 hv[4][2];
  f32x4 rmax[4];
#pragma unroll
  for (int mi = 0; mi < 4; ++mi) {
#pragma unroll
    for (int ni = 0; ni < 2; ++ni)
#pragma unroll
      for (int j = 0; j < 4; ++j) {
        float g = accg[mi][ni][j];
        float u = accu[mi][ni][j];
        float h = (g / (1.f + expf(-g))) * u;
        hv[mi][ni][j] = h;
        float ah = fabsf(h);
        rmax[mi][j] = (ni == 0) ? ah : fmaxf(rmax[mi][j], ah);
      }
#pragma unroll
    for (int d = 1; d < 16; d <<= 1)
#pragma unroll
      for (int j = 0; j < 4; ++j)
        rmax[mi][j] = fmaxf(rmax[mi][j], __shfl_xor(rmax[mi][j], d));
  }
  __syncthreads();
  if ((lane & 15) == 0) {
#pragma unroll
    for (int mi = 0; mi < 4; ++mi)
#pragma unroll
      for (int j = 0; j < 4; ++j) {
        int row = wr * 64 + mi * 16 + ((lane >> 4) << 2) + j;
        amx[row * 4 + wc] = rmax[mi][j];
      }
  }
  __syncthreads();
  const int Mrem = M - mt * 128;
#pragma unroll
  for (int mi = 0; mi < 4; ++mi)
#pragma unroll
    for (int j = 0; j < 4; ++j) {
      const int row = wr * 64 + mi * 16 + ((lane >> 4) << 2) + j;
      f32x4 a4 = *(const f32x4*)(amx + row * 4);
      float am = fmaxf(fmaxf(a4[0], a4[1]), fmaxf(a4[2], a4[3]));
      float s = fmaxf(am, 1e-12f) / 448.f;
      if (row < Mrem) {
        const int slot = slots[row];
        uint8_t* hp = hq + (size_t)slot * IDIM + nb * 128 + wc * 32 + (lane & 15);
        hp[0]  = (uint8_t)f8_1(hv[mi][0][j] / s);
        hp[16] = (uint8_t)f8_1(hv[mi][1][j] / s);
        if (wc == 0 && (lane & 15) == 0) hs[slot * 11 + nb] = s;
      }
    }
}

// ============ kernel 4: down GEMM (fp8 MFMA, block scales) + rw-weighted scatter-add ============
__global__ __launch_bounds__(512) void gemm2_kernel(
    const uint8_t* __restrict__ hq, const float* __restrict__ hs,
    const uint8_t* __restrict__ w, const float* __restrict__ wscl,
    const int* __restrict__ list, const int* __restrict__ cnt,
    const float* __restrict__ tkw, float* __restrict__ out) {
  const int e = blockIdx.z, mt = blockIdx.y, nt = blockIdx.x;
  const int M = cnt[e];
  if (mt * 128 >= M) return;
  __shared__ __align__(16) uint8_t As[128 * LDA];
  __shared__ __align__(16) uint8_t Bs[256 * LDA];
  __shared__ int slots[128];
  __shared__ float rwl[128];
  __shared__ __align__(16) float sxs[128];
  const int tid = threadIdx.x, lane = tid & 63, wid = tid >> 6;
  const int wr = wid >> 2, wc = wid & 3;
  if (tid < 128) {
    int m = mt * 128 + tid;
    int slot = list[e * MAXM + (m < M ? m : 0)];
    slots[tid] = slot;
    rwl[tid] = (m < M) ? tkw[slot] : 0.f;
  }
  __syncthreads();
  const int srow = tid >> 3;
  const int cj = (tid & 7) << 4;
  const long slotA0 = slots[srow];
  const long slotA1 = slots[srow + 64];
  const int my_slot = (tid < 128) ? slots[tid] : 0;
  const uint8_t* pA0 = hq + slotA0 * IDIM + cj;
  const uint8_t* pA1 = hq + slotA1 * IDIM + cj;
  const uint8_t* pB = w + (size_t)e * HDIM * IDIM + (size_t)(nt * 256 + srow) * IDIM + cj;
  const float* wsd = wscl + (size_t)e * 176 + (nt * 2 + (wc >> 1)) * 11;  // (E,16,11)
  const float* pSX = hs + (size_t)my_slot * 11;
  f32x4 acc[4][4] = {};
  const int kbyte = (lane >> 4) << 3;
  f32x4 ra0, ra1, rb0, rb1, rb2, rb3;
  float rs;
  ra0 = *(const f32x4*)(pA0);
  ra1 = *(const f32x4*)(pA1);
  rb0 = *(const f32x4*)(pB);
  rb1 = *(const f32x4*)(pB + (size_t)64 * IDIM);
  rb2 = *(const f32x4*)(pB + (size_t)128 * IDIM);
  rb3 = *(const f32x4*)(pB + (size_t)192 * IDIM);
  rs = (tid < 128) ? pSX[0] : 0.f;
  for (int kb = 0; kb < NKB2; ++kb) {
    __syncthreads();
    *(f32x4*)(As + srow * LDA + cj) = ra0;
    *(f32x4*)(As + (srow + 64) * LDA + cj) = ra1;
    *(f32x4*)(Bs + srow * LDA + cj) = rb0;
    *(f32x4*)(Bs + (srow + 64) * LDA + cj) = rb1;
    *(f32x4*)(Bs + (srow + 128) * LDA + cj) = rb2;
    *(f32x4*)(Bs + (srow + 192) * LDA + cj) = rb3;
    if (tid < 128) sxs[tid] = rs;
    __syncthreads();
    if (kb + 1 < NKB2) {
      const int ko = (kb + 1) << 7;
      ra0 = *(const f32x4*)(pA0 + ko);
      ra1 = *(const f32x4*)(pA1 + ko);
      rb0 = *(const f32x4*)(pB + ko);
      rb1 = *(const f32x4*)(pB + (size_t)64 * IDIM + ko);
      rb2 = *(const f32x4*)(pB + (size_t)128 * IDIM + ko);
      rb3 = *(const f32x4*)(pB + (size_t)192 * IDIM + ko);
      rs = (tid < 128) ? pSX[kb + 1] : 0.f;
    }
    const float swd = wsd[kb];
    long af[4][4], bf[4][4];
#pragma unroll
    for (int mi = 0; mi < 4; ++mi) {
      const int r = wr * 64 + mi * 16 + (lane & 15);
      const uint8_t* bp = As + r * LDA;
#pragma unroll
      for (int kc = 0; kc < 4; ++kc)
        af[mi][kc] = *(const long*)(bp + (kc << 5) + kbyte);
    }
#pragma unroll
    for (int ni = 0; ni < 4; ++ni) {
      const int r = wc * 64 + ni * 16 + (lane & 15);
      const uint8_t* bp = Bs + r * LDA;
#pragma unroll
      for (int kc = 0; kc < 4; ++kc)
        bf[ni][kc] = *(const long*)(bp + (kc << 5) + kbyte);
    }
    f32x4 sx[4];
#pragma unroll
    for (int mi = 0; mi < 4; ++mi)
      sx[mi] = *(const f32x4*)(sxs + wr * 64 + mi * 16 + ((lane >> 4) << 2));
#pragma unroll
    for (int mi = 0; mi < 4; ++mi)
#pragma unroll
      for (int ni = 0; ni < 4; ++ni) {
        f32x4 p = {0.f, 0.f, 0.f, 0.f};
#pragma unroll
        for (int kc = 0; kc < 4; ++kc) p = mfma_fp8(af[mi][kc], bf[ni][kc], p);
#pragma unroll
        for (int j = 0; j < 4; ++j) acc[mi][ni][j] += p[j] * (sx[mi][j] * swd);
      }
  }
  const int Mrem = M - mt * 128;
#pragma unroll
  for (int mi = 0; mi < 4; ++mi)
#pragma unroll
    for (int j = 0; j < 4; ++j) {
      const int row = wr * 64 + mi * 16 + ((lane >> 4) << 2) + j;
      if (row < Mrem) {
        const int slot = slots[row];
        const float rw = rwl[row];
        float* op = out + (size_t)(slot >> 1) * HDIM + nt * 256 + wc * 64 + (lane & 15);
#pragma unroll
        for (int ni = 0; ni < 4; ++ni) atomicAdd(op + ni * 16, rw * acc[mi][ni][j]);
      }
    }
}

extern "C" void kernel_launch(void* const* d_in, const int* in_sizes, int n_in,
                              void* d_out, int out_size, void* d_ws, size_t ws_size,
                              hipStream_t stream) {
  const float* hidden = (const float*)d_in[0];
  const void* topk_idx = d_in[1];
  const float* topk_w = (const float*)d_in[2];
  const void* gup_raw = d_in[3];   // fp8 values held as f32 or bf16 (sniffed)
  const float* gup_s = (const float*)d_in[4];
  const void* dwn_raw = d_in[5];
  const float* dwn_s = (const float*)d_in[6];
  float* out = (float*)d_out;
  uint8_t* ws = (uint8_t*)d_ws;
  // workspace layout (~79.6 MB)
  uint8_t* xq = ws;                           //  4,194,304
  float* xs = (float*)(ws + 4194304);         //    131,072
  uint8_t* hq = ws + 4325376;                 //  5,767,168
  float* hs = (float*)(ws + 10092544);        //    180,224
  int* list = (int*)(ws + 10272768);          //    131,072
  int* cnt = (int*)(ws + 10403840);           //         64
  int* modes = (int*)(ws + 10403904);         //         64
  uint8_t* gq = ws + 10403968;                // 46,137,344 (gate_up fp8)
  uint8_t* dq = ws + 56541312;                // 23,068,672 (down fp8)
  (void)in_sizes; (void)n_in; (void)ws_size;

  zero_kernel<<<4096, 256, 0, stream>>>(out, cnt);
  sniff_kernel<<<1, 64, 0, stream>>>((const uint16_t*)gup_raw, (const uint16_t*)dwn_raw, modes);
  repack_kernel<<<(5767168 + 255) / 256, 256, 0, stream>>>(gup_raw, gq, 5767168, modes, 0);
  repack_kernel<<<(2883584 + 255) / 256, 256, 0, stream>>>(dwn_raw, dq, 2883584, modes, 1);
  quantx_kernel<<<8192, 256, 0, stream>>>(hidden, xq, xs);
  route_kernel<<<16, 256, 0, stream>>>(topk_idx, list, cnt);
  gemm1_kernel<<<dim3(NNB1, MAXM / 128, NEXP), 512, 0, stream>>>(xq, xs, gq, gup_s, list, cnt, hq, hs);
  gemm2_kernel<<<dim3(HDIM / 256, MAXM / 128, NEXP), 512, 0, stream>>>(hq, hs, dq, dwn_s, list, cnt, topk_w, out);
}